// Round 16
// baseline (60.564 us; speedup 1.0000x reference)
//
#include <hip/hip_runtime.h>

#define BAND 16
#define NITER (BAND + 4)
#define NSLOT 1024

__global__ __launch_bounds__(64) void nms_loss_kernel(
    const float* __restrict__ tl, const float* __restrict__ pl,
    double* __restrict__ acc_d, float* __restrict__ acc_f,
    int H, int W)
{
    const int y0   = blockIdx.x * BAND;
    const int slab = blockIdx.y;               // 256-col slab
    const int ch   = blockIdx.z;
    const float* tc = tl + (size_t)ch * H * W;
    const float* pc = pl + (size_t)ch * H * W;
    const int tid = threadIdx.x;               // 0..63, one wave per block
    const int c0  = (slab << 8) + (tid << 2);  // 4 output columns per thread
    const int oa  = max(c0 - 4, 0);            // aligned float4 bases (4-col aligned)
    const int oc  = min(c0 + 4, W - 4);
    const bool eL = (c0 == 0), eR = (c0 == W - 4);
    const float eL2 = eL ? 2.f : 0.f, eR2 = eR ? 2.f : 0.f;

    // register rings: P (5 rows x 4 px), e (3 rows x 6 cols), mask (3 rows x 4 px)
    float P1h[5][4], P2h[5][4], P3h[5][4];
    float eh[3][6], tch[3][4];
    // pending row (prefetch distance 1, R12-proven): t cols c0-2..c0+5 in t12[2..9],
    // p cols c0-1..c0+4 in p12[3..8]; slot t12[4+k] <-> col c0+k
    float t12[12], p12[12];

    // Ghost placement makes interior H-formulas exact at x-edges (derived from the
    // validated border tables; hdd residual handled by the eL2/eR2 fixup fmas).
    #define LOADROW(I) {                                                            \
        int tr_ = y0 - 2 + (I); tr_ = min(max(tr_, 0), H - 1);                       \
        int pr_ = y0 - 3 + (I); pr_ = pr_ < 0 ? -pr_ : (pr_ >= H ? 2*H-2-pr_ : pr_); \
        const float* tb_ = tc + (size_t)tr_ * W;                                     \
        const float* pb_ = pc + (size_t)pr_ * W;                                     \
        float4 a_ = *(const float4*)(tb_ + oa);                                      \
        float4 b_ = *(const float4*)(tb_ + c0);                                      \
        float4 c_ = *(const float4*)(tb_ + oc);                                      \
        t12[2]=a_.z; t12[3]=a_.w;                                                    \
        t12[4]=b_.x; t12[5]=b_.y; t12[6]=b_.z; t12[7]=b_.w;                          \
        t12[8]=c_.x; t12[9]=c_.y;                                                    \
        a_ = *(const float4*)(pb_ + oa);                                             \
        b_ = *(const float4*)(pb_ + c0);                                             \
        c_ = *(const float4*)(pb_ + oc);                                             \
        p12[3]=a_.w;                                                                 \
        p12[4]=b_.x; p12[5]=b_.y; p12[6]=b_.z; p12[7]=b_.w;                          \
        p12[8]=c_.x;                                                                 \
        t12[2] = eL ? t12[5] : t12[2];   /* ghost(-2)=t1 */                          \
        t12[3] = eL ? t12[4] : t12[3];   /* ghost(-1)=t0 */                          \
        t12[8] = eR ? t12[7] : t12[8];   /* ghost(W)  =t(W-1) */                     \
        t12[9] = eR ? t12[6] : t12[9];   /* ghost(W+1)=t(W-2) */                     \
        p12[3] = eL ? p12[5] : p12[3];   /* e reflect(-1)=col 1 */                   \
        p12[8] = eR ? p12[6] : p12[8]; } /* e reflect(W)=col W-2 */

    LOADROW(0)

    float partial = 0.f;

    #pragma unroll
    for (int i = 0; i < NITER; ++i) {
        const int sP = i % 5, sE = i % 3;

        // ---- consume pending row (branch-free, uniform across all lanes) ----
        #pragma unroll
        for (int j = 0; j < 4; ++j) {
            float a0 = t12[j+2], a1 = t12[j+3], a2 = t12[j+4], a3 = t12[j+5], a4 = t12[j+6];
            float s04 = a0 + a4, s13 = a1 + a3;
            P1h[sP][j] = fmaf(-2.f, a2, s04);                       // hdd
            P3h[sP][j] = fmaf(6.f, a2, fmaf(4.f, s13, s04));        // hss
            P2h[sP][j] = fmaf(2.f, a3 - a1, a4 - a0);               // hds
            tch[sE][j] = a2;
        }
        // hdd edge residuals (only x=0 and x=W-1 lanes have nonzero eL2/eR2)
        P1h[sP][0] = fmaf(eL2, t12[4] - t12[5], P1h[sP][0]);
        P1h[sP][3] = fmaf(eR2, t12[7] - t12[6], P1h[sP][3]);
        #pragma unroll
        for (int m = 0; m < 6; ++m) eh[sE][m] = __expf(0.1f * p12[m+3]);

        // ---- issue next-row loads (latency hides under output phase) ----
        if (i + 1 < NITER) LOADROW(i + 1)

        // ---- output row y = y0 + i - 4 ----
        if (i >= 4) {
            const int y = y0 + i - 4;
            const int s0=(i-4)%5, s1=(i-3)%5, s2=(i-2)%5, s3=(i-1)%5, s4=i%5;
            const int et=(i-2)%3, em=(i-1)%3, eb=i%3;   // e rows y-1, y, y+1
            const bool ytop = (y == 0), ybot = (y == H - 1);
            #pragma unroll
            for (int j = 0; j < 4; ++j) {
                // interior vertical on (row-clamped) P slots — exact at y=1,H-2;
                // y=0 / y=H-1 need the slot fixups below (derived from tables)
                float a04 = P1h[s0][j] + P1h[s4][j], a13 = P1h[s1][j] + P1h[s3][j];
                float xx = fmaf(6.f, P1h[s2][j], fmaf(4.f, a13, a04));   // wss
                float xy = fmaf(2.f, P2h[s3][j] - P2h[s1][j], P2h[s4][j] - P2h[s0][j]); // wsd
                float yy = fmaf(-2.f, P3h[s2][j], P3h[s0][j] + P3h[s4][j]);             // wdd
                if (ytop) {
                    xx += P1h[s3][j] - P1h[s2][j];
                    xy += P2h[s3][j] - P2h[s2][j];
                    yy += P3h[s2][j] - P3h[s3][j];
                } else if (ybot) {
                    xx += P1h[s1][j] - P1h[s2][j];
                    xy += P2h[s2][j] - P2h[s1][j];
                    yy += P3h[s2][j] - P3h[s1][j];
                }
                if (tch[et][j] > 0.f) {          // mask at row y
                    float den = xx + 6.4e-6f;     // 64*(grad_xx+1e-7)
                    float sa  = 6.4e-6f - xy;     // 64*(1e-7-grad_xy)
                    float ax = fabsf(den), ay = fabsf(yy);
                    bool isH = ay < 0.41421356f * ax;    // tan(22.5)
                    bool isV = ay >= 2.41421356f * ax;   // tan(67.5)
                    bool qp  = ((yy * sa) * den) > 0.f;  // sign of q
                    float ec = eh[em][j + 1];            // e col x
                    float n1 = isH ? eh[em][j + 2] : (isV ? eh[eb][j + 1] : (qp ? eh[eb][j] : eh[eb][j + 2]));
                    float n2 = isH ? eh[em][j]     : (isV ? eh[et][j + 1] : (qp ? eh[et][j + 2] : eh[et][j]));
                    partial += __logf(__fdividef(ec, ec + n1 + n2 + 1e-7f));
                }
            }
        }
    }

    // ---- wave reduction + spread atomics (single wave, no barriers) ----
    for (int off = 32; off > 0; off >>= 1)
        partial += __shfl_down(partial, off, 64);
    if (tid == 0) {
        int fid = (blockIdx.z * gridDim.y + blockIdx.y) * gridDim.x + blockIdx.x;
        if (acc_d) atomicAdd(&acc_d[fid & (NSLOT - 1)], (double)partial);
        else       atomicAdd(acc_f, partial);
    }
}

__global__ void finalize_kernel(const double* acc_d, float* out,
                                int use_double, float inv_b)
{
    if (use_double) {
        int l = threadIdx.x;
        double s = 0.0;
        for (int i = l; i < NSLOT; i += 64) s += acc_d[i];
        for (int off = 32; off > 0; off >>= 1) s += __shfl_down(s, off, 64);
        if (l == 0) out[0] = (float)(-s * (double)inv_b);
    } else {
        if (threadIdx.x == 0) out[0] = -out[0] * inv_b;
    }
}

extern "C" void kernel_launch(void* const* d_in, const int* in_sizes, int n_in,
                              void* d_out, int out_size, void* d_ws, size_t ws_size,
                              hipStream_t stream)
{
    const float* tl = (const float*)d_in[0];
    const float* pl = (const float*)d_in[1];
    float* out = (float*)d_out;

    const int H = 512, W = 512, B = 4;

    double* acc_d = nullptr;
    float* acc_f = nullptr;
    int use_double = 0;
    if (ws_size >= NSLOT * sizeof(double)) {
        acc_d = (double*)d_ws;
        use_double = 1;
        hipMemsetAsync(acc_d, 0, NSLOT * sizeof(double), stream);
    } else {
        acc_f = out;
        hipMemsetAsync(out, 0, sizeof(float), stream);
    }

    // 32 bands x 2 slabs x 76 channels = 4864 single-wave blocks, 4 px/thread
    dim3 grid(H / BAND, W / 256, 76);
    nms_loss_kernel<<<grid, 64, 0, stream>>>(tl, pl, acc_d, acc_f, H, W);
    finalize_kernel<<<1, 64, 0, stream>>>(acc_d, out, use_double, 1.0f / (float)B);
}